// Round 1
// baseline (755.676 us; speedup 1.0000x reference)
//
#include <hip/hip_runtime.h>
#include <hip/hip_bf16.h>

#define B_ 4
#define K_ 2048
#define D_ 512
#define H_ 8
#define DQ_ 64
#define DV_ 64
#define ATTN_ 128

// ---------------------------------------------------------------------------
// GEMM: C[M,N] = X[M,Kd] @ W[N,Kd]^T + bias[N]
// 64x64 output tile, TK=32, 256 threads, 4x4 acc per thread. fp32.
// ---------------------------------------------------------------------------
__global__ __launch_bounds__(256)
void gemm_xwt(const float* __restrict__ X, const float* __restrict__ W,
              const float* __restrict__ bias, float* __restrict__ C,
              int M, int N, int Kd)
{
    const int TK = 32;
    __shared__ float Xs[64][33];   // +1 pad: conflict-free column reads
    __shared__ float Ws[64][33];
    const int bm = blockIdx.x * 64;
    const int bn = blockIdx.y * 64;
    const int tid = threadIdx.x;
    const int tx = tid & 15;       // 16 thread-cols
    const int ty = tid >> 4;       // 16 thread-rows

    float acc[4][4] = {{0.f}};

    for (int k0 = 0; k0 < Kd; k0 += TK) {
        #pragma unroll
        for (int it = 0; it < 2; ++it) {        // 512 float4 / 256 threads
            int f = tid + it * 256;
            int r = f >> 3;                      // / (TK/4)
            int c = f & 7;
            float4 xv = *reinterpret_cast<const float4*>(
                &X[(size_t)(bm + r) * Kd + k0 + c * 4]);
            Xs[r][c*4+0] = xv.x; Xs[r][c*4+1] = xv.y;
            Xs[r][c*4+2] = xv.z; Xs[r][c*4+3] = xv.w;
            float4 wv = *reinterpret_cast<const float4*>(
                &W[(size_t)(bn + r) * Kd + k0 + c * 4]);
            Ws[r][c*4+0] = wv.x; Ws[r][c*4+1] = wv.y;
            Ws[r][c*4+2] = wv.z; Ws[r][c*4+3] = wv.w;
        }
        __syncthreads();
        #pragma unroll
        for (int kk = 0; kk < TK; ++kk) {
            float a[4], bv[4];
            #pragma unroll
            for (int i2 = 0; i2 < 4; ++i2) a[i2]  = Xs[ty*4 + i2][kk];
            #pragma unroll
            for (int j2 = 0; j2 < 4; ++j2) bv[j2] = Ws[tx*4 + j2][kk];
            #pragma unroll
            for (int i2 = 0; i2 < 4; ++i2)
                #pragma unroll
                for (int j2 = 0; j2 < 4; ++j2)
                    acc[i2][j2] += a[i2] * bv[j2];
        }
        __syncthreads();
    }

    const int col = bn + tx * 4;
    float4 bb = *reinterpret_cast<const float4*>(&bias[col]);
    #pragma unroll
    for (int i2 = 0; i2 < 4; ++i2) {
        int row = bm + ty * 4 + i2;
        float4 o;
        o.x = acc[i2][0] + bb.x;
        o.y = acc[i2][1] + bb.y;
        o.z = acc[i2][2] + bb.z;
        o.w = acc[i2][3] + bb.w;
        *reinterpret_cast<float4*>(&C[(size_t)row * N + col]) = o;
    }
}

// ---------------------------------------------------------------------------
// Banded-causal local attention (window 129, scale 1/sqrt(K)).
// grid (K/256, H, B), block 256. Thread owns query row i = i0 + tid.
// ---------------------------------------------------------------------------
__global__ __launch_bounds__(256)
void attn_local(const float* __restrict__ q, const float* __restrict__ k,
                const float* __restrict__ v, float* __restrict__ o)
{
    __shared__ float ks[64][64];
    __shared__ float vs[64][64];
    const int b  = blockIdx.z;
    const int h  = blockIdx.y;
    const int i0 = blockIdx.x * 256;
    const int tid = threadIdx.x;
    const int i  = i0 + tid;
    const int w  = tid >> 6;                 // wave id 0..3
    const float scale = 0.0220970869120796f; // 1/sqrt(2048)

    float qf[64];
    {
        const float4* qr = reinterpret_cast<const float4*>(
            q + ((size_t)(b * K_ + i) * H_ + h) * DQ_);
        #pragma unroll
        for (int d4 = 0; d4 < 16; ++d4) {
            float4 t = qr[d4];
            qf[d4*4+0] = t.x; qf[d4*4+1] = t.y;
            qf[d4*4+2] = t.z; qf[d4*4+3] = t.w;
        }
    }

    float acc[64];
    #pragma unroll
    for (int d = 0; d < 64; ++d) acc[d] = 0.f;
    float l = 0.f;

    for (int c = -2; c <= 3; ++c) {
        const int j0 = i0 + 64 * c;
        #pragma unroll
        for (int it = 0; it < 4; ++it) {     // 1024 float4 / 256 threads
            int f  = tid + it * 256;
            int r  = f >> 4;
            int cc = f & 15;
            int j  = j0 + r;
            float4 kv = make_float4(0.f, 0.f, 0.f, 0.f);
            float4 vv = make_float4(0.f, 0.f, 0.f, 0.f);
            if (j >= 0) {                    // j < K_ guaranteed by geometry
                kv = *reinterpret_cast<const float4*>(
                    &k[((size_t)(b * K_ + j) * H_ + h) * DQ_ + cc * 4]);
                vv = *reinterpret_cast<const float4*>(
                    &v[((size_t)(b * K_ + j) * H_ + h) * DV_ + cc * 4]);
            }
            ks[r][cc*4+0] = kv.x; ks[r][cc*4+1] = kv.y;
            ks[r][cc*4+2] = kv.z; ks[r][cc*4+3] = kv.w;
            vs[r][cc*4+0] = vv.x; vs[r][cc*4+1] = vv.y;
            vs[r][cc*4+2] = vv.z; vs[r][cc*4+3] = vv.w;
        }
        __syncthreads();

        if (c >= w - 2 && c <= w) {          // wave-uniform chunk skip
            #pragma unroll 2
            for (int jj = 0; jj < 64; ++jj) {
                const int j = j0 + jj;
                const float4* kr = reinterpret_cast<const float4*>(&ks[jj][0]);
                float s = 0.f;
                #pragma unroll
                for (int d4 = 0; d4 < 16; ++d4) {
                    float4 t = kr[d4];
                    s += qf[d4*4+0]*t.x + qf[d4*4+1]*t.y
                       + qf[d4*4+2]*t.z + qf[d4*4+3]*t.w;
                }
                const bool ok = (j >= 0) && (j <= i) && (j >= i - ATTN_);
                const float sm = ok ? s * scale : -1e30f;
                const float p  = __expf(fminf(sm, 60.f));  // exp(-1e30)=0
                l += p;
                const float4* vr = reinterpret_cast<const float4*>(&vs[jj][0]);
                #pragma unroll
                for (int d4 = 0; d4 < 16; ++d4) {
                    float4 t = vr[d4];
                    acc[d4*4+0] += p * t.x; acc[d4*4+1] += p * t.y;
                    acc[d4*4+2] += p * t.z; acc[d4*4+3] += p * t.w;
                }
            }
        }
        __syncthreads();
    }

    const float inv = 1.f / l;
    float* orow = o + ((size_t)(b * K_ + i) * H_ + h) * DV_;
    #pragma unroll
    for (int d4 = 0; d4 < 16; ++d4) {
        float4 t;
        t.x = acc[d4*4+0] * inv; t.y = acc[d4*4+1] * inv;
        t.z = acc[d4*4+2] * inv; t.w = acc[d4*4+3] * inv;
        reinterpret_cast<float4*>(orow)[d4] = t;
    }
}

// ---------------------------------------------------------------------------
extern "C" void kernel_launch(void* const* d_in, const int* in_sizes, int n_in,
                              void* d_out, int out_size, void* d_ws, size_t ws_size,
                              hipStream_t stream)
{
    const float* query = (const float*)d_in[0];
    const float* key   = (const float*)d_in[1];
    const float* value = (const float*)d_in[2];
    const float* W_q   = (const float*)d_in[3];
    const float* b_q   = (const float*)d_in[4];
    const float* W_k   = (const float*)d_in[5];
    const float* b_k   = (const float*)d_in[6];
    const float* W_v   = (const float*)d_in[7];
    const float* b_v   = (const float*)d_in[8];
    const float* W_o   = (const float*)d_in[9];
    const float* b_o   = (const float*)d_in[10];
    float* out = (float*)d_out;

    const int M = B_ * K_;                      // 8192
    const size_t SZ = (size_t)M * (H_ * DQ_);   // 8192*512 floats
    float* qp = (float*)d_ws;
    float* kp = qp + SZ;
    float* vp = kp + SZ;
    float* ap = qp;  // attention out aliases q buffer (race-free; see analysis)

    dim3 gg(M / 64, (H_ * DQ_) / 64);           // 128 x 8
    dim3 blk(256);

    gemm_xwt<<<gg, blk, 0, stream>>>(query, W_q, b_q, qp, M, H_*DQ_, D_);
    gemm_xwt<<<gg, blk, 0, stream>>>(key,   W_k, b_k, kp, M, H_*DQ_, D_);
    gemm_xwt<<<gg, blk, 0, stream>>>(value, W_v, b_v, vp, M, H_*DV_, D_);

    attn_local<<<dim3(K_ / 256, H_, B_), blk, 0, stream>>>(qp, kp, vp, ap);

    gemm_xwt<<<gg, blk, 0, stream>>>(ap, W_o, b_o, out, M, D_, H_ * DV_);
}

// Round 2
// 156.749 us; speedup vs baseline: 4.8209x; 4.8209x over previous
//
#include <hip/hip_runtime.h>
#include <hip/hip_bf16.h>
#include <stdint.h>

#define B_ 4
#define K_ 2048
#define D_ 512
#define H_ 8
#define ATTN_ 128
#define M_ (B_ * K_)   // 8192

typedef __attribute__((ext_vector_type(4))) float f32x4;
typedef __attribute__((ext_vector_type(8))) short bf16x8;
typedef __attribute__((ext_vector_type(8))) unsigned short u16x8;

__device__ __forceinline__ unsigned short f2bf(float f) {
    union { float f; unsigned int i; } x; x.f = f;
    unsigned int r = x.i + 0x7fffu + ((x.i >> 16) & 1u);   // RNE
    return (unsigned short)(r >> 16);
}
__device__ __forceinline__ float bf2f(unsigned short u) {
    union { unsigned int i; float f; } x; x.i = ((unsigned int)u) << 16; return x.f;
}
__device__ __forceinline__ void gload_lds16(const unsigned short* g, unsigned short* l) {
    __builtin_amdgcn_global_load_lds(
        (const __attribute__((address_space(1))) void*)g,
        (__attribute__((address_space(3))) void*)l, 16, 0, 0);
}

// ---------------------------------------------------------------------------
// fp32 -> bf16 conversion, multi-tensor (blockIdx.y picks the job)
// ---------------------------------------------------------------------------
struct Cvt { const float* s; unsigned short* d; int n8; };
struct CvtA { Cvt c[5]; };

__global__ __launch_bounds__(256)
void cvt_multi(CvtA a) {
    const Cvt c = a.c[blockIdx.y];
    const float4* s4 = (const float4*)c.s;
    u16x8* d8 = (u16x8*)c.d;
    for (int g = blockIdx.x * 256 + threadIdx.x; g < c.n8; g += gridDim.x * 256) {
        float4 f0 = s4[2 * g], f1 = s4[2 * g + 1];
        u16x8 o;
        o[0] = f2bf(f0.x); o[1] = f2bf(f0.y); o[2] = f2bf(f0.z); o[3] = f2bf(f0.w);
        o[4] = f2bf(f1.x); o[5] = f2bf(f1.y); o[6] = f2bf(f1.z); o[7] = f2bf(f1.w);
        d8[g] = o;
    }
}

// ---------------------------------------------------------------------------
// bf16 MFMA GEMM: C[8192,512] = A[8192,512] @ W[512,512]^T + bias
// 128x128 tile, BK=64, 512 threads (8 waves, 4m x 2n, wave tile 32x64).
// global_load_lds(16B) staging, linear LDS dest + inverse-swizzled global
// source; ds_read applies chunk ^= (row&7) -> 2-way conflicts only (free).
// 2-phase double-buffer (T3 minimum recipe).
// ---------------------------------------------------------------------------
template<bool OUT_BF16>
__global__ __launch_bounds__(512)
void gemm_bf16k(const unsigned short* __restrict__ A,
                const unsigned short* __restrict__ W,
                const float* __restrict__ bias,
                void* __restrict__ C)
{
    __shared__ unsigned short As[2][128 * 64];
    __shared__ unsigned short Bs[2][128 * 64];

    const int id  = blockIdx.x;
    const int swz = (id & 7) * 32 + (id >> 3);   // XCD-contiguous (256%8==0)
    const int bm  = (swz & 63) * 128;
    const int bn  = (swz >> 6) * 128;

    const int tid = threadIdx.x;
    const int w   = tid >> 6;          // wave 0..7
    const int l   = tid & 63;
    const int lr  = l & 15;
    const int lhi = l >> 4;            // 0..3
    const int wm  = (w >> 1) * 32;     // wave row offset (4 rows of waves)
    const int wn  = (w & 1) * 64;      // wave col offset (2 cols of waves)

    f32x4 acc[2][4];
    #pragma unroll
    for (int i = 0; i < 2; ++i)
        #pragma unroll
        for (int j = 0; j < 4; ++j) acc[i][j] = (f32x4){0.f, 0.f, 0.f, 0.f};

    auto stage = [&](int buf, int t) {
        const int k0 = t * 64;
        #pragma unroll
        for (int it = 0; it < 2; ++it) {         // A: wave stages 16 rows
            const int f  = it * 64 + l;
            const int r  = w * 16 + (f >> 3);
            const int cs = (f & 7) ^ (r & 7);    // inverse-swizzled source chunk
            gload_lds16(A + (size_t)(bm + r) * D_ + k0 + cs * 8,
                        &As[buf][(w * 128 + it * 64) * 8]);
        }
        #pragma unroll
        for (int it = 0; it < 2; ++it) {         // B (W rows = N)
            const int f  = it * 64 + l;
            const int r  = w * 16 + (f >> 3);
            const int cs = (f & 7) ^ (r & 7);
            gload_lds16(W + (size_t)(bn + r) * D_ + k0 + cs * 8,
                        &Bs[buf][(w * 128 + it * 64) * 8]);
        }
    };

    stage(0, 0);
    __syncthreads();                             // drains vmcnt(0)

    int buf = 0;
    for (int t = 0; t < 8; ++t) {                // K = 512 = 8 x 64
        if (t < 7) stage(buf ^ 1, t + 1);        // async prefetch next tile
        #pragma unroll
        for (int kk = 0; kk < 2; ++kk) {         // two K=32 halves
            bf16x8 af[2], bfr[4];
            #pragma unroll
            for (int fm = 0; fm < 2; ++fm) {
                const int row = wm + fm * 16 + lr;
                const int ch  = (kk * 4 + lhi) ^ (lr & 7);   // swizzled read
                af[fm] = *(const bf16x8*)&As[buf][row * 64 + ch * 8];
            }
            #pragma unroll
            for (int fn = 0; fn < 4; ++fn) {
                const int row = wn + fn * 16 + lr;
                const int ch  = (kk * 4 + lhi) ^ (lr & 7);
                bfr[fn] = *(const bf16x8*)&Bs[buf][row * 64 + ch * 8];
            }
            #pragma unroll
            for (int fm = 0; fm < 2; ++fm)
                #pragma unroll
                for (int fn = 0; fn < 4; ++fn)
                    acc[fm][fn] = __builtin_amdgcn_mfma_f32_16x16x32_bf16(
                        af[fm], bfr[fn], acc[fm][fn], 0, 0, 0);
        }
        __syncthreads();                         // vmcnt(0): prefetch landed
        buf ^= 1;
    }

    float bv[4];
    #pragma unroll
    for (int fn = 0; fn < 4; ++fn) bv[fn] = bias[bn + wn + fn * 16 + lr];

    #pragma unroll
    for (int fm = 0; fm < 2; ++fm)
        #pragma unroll
        for (int fn = 0; fn < 4; ++fn)
            #pragma unroll
            for (int rr = 0; rr < 4; ++rr) {
                const int row = bm + wm + fm * 16 + lhi * 4 + rr;  // C/D: row=(l>>4)*4+reg
                const int col = bn + wn + fn * 16 + lr;            //      col=l&15
                const float val = acc[fm][fn][rr] + bv[fn];
                if (OUT_BF16)
                    ((unsigned short*)C)[(size_t)row * 512 + col] = f2bf(val);
                else
                    ((float*)C)[(size_t)row * 512 + col] = val;
            }
}

// ---------------------------------------------------------------------------
// Banded-causal local attention, bf16 in/out. 64 query rows per block,
// 4 lanes per row (16 dims each) -> no register spill. K/V window (192 rows)
// staged in LDS with chunk^=(row&7) XOR swizzle (else 16-way bank conflict).
// Score reduced over the 4-lane group via shfl_xor. No online max needed:
// scale is 1/sqrt(2048), |s*scale| << 80.
// ---------------------------------------------------------------------------
__global__ __launch_bounds__(256)
void attn_local_bf16(const unsigned short* __restrict__ qb,
                     const unsigned short* __restrict__ kb,
                     const unsigned short* __restrict__ vb,
                     unsigned short* __restrict__ ob)
{
    __shared__ unsigned short ks[192 * 64];
    __shared__ unsigned short vs[192 * 64];
    const int b  = blockIdx.z;
    const int h  = blockIdx.y;
    const int i0 = blockIdx.x * 64;
    const int tid = threadIdx.x;
    const int row_in = tid >> 2;                 // 0..63
    const int c4 = tid & 3;                      // lane-in-group
    const int i  = i0 + row_in;
    const int j0 = i0 - 128;
    const float scale = 0.0220970869120796f;     // 1/sqrt(2048)

    // stage K/V window rows [i0-128, i0+63], zero-fill j<0
    #pragma unroll
    for (int it = 0; it < 6; ++it) {             // 1536 chunks / 256 threads
        const int f = it * 256 + tid;
        const int r = f >> 3, c = f & 7;
        const int j = j0 + r;
        const int cs = c ^ (r & 7);              // swizzled LDS position
        u16x8 kv = {0,0,0,0,0,0,0,0}, vv = {0,0,0,0,0,0,0,0};
        if (j >= 0) {
            const size_t base = ((size_t)(b * K_ + j) * H_ + h) * 64 + c * 8;
            kv = *(const u16x8*)&kb[base];
            vv = *(const u16x8*)&vb[base];
        }
        *(u16x8*)&ks[r * 64 + cs * 8] = kv;
        *(u16x8*)&vs[r * 64 + cs * 8] = vv;
    }

    // q fragment (16 dims) -> f32 regs
    float qf[16];
    {
        const size_t qbase = ((size_t)(b * K_ + i) * H_ + h) * 64 + c4 * 16;
        u16x8 a0 = *(const u16x8*)&qb[qbase];
        u16x8 a1 = *(const u16x8*)&qb[qbase + 8];
        #pragma unroll
        for (int d = 0; d < 8; ++d) { qf[d] = bf2f(a0[d]); qf[8 + d] = bf2f(a1[d]); }
    }
    __syncthreads();

    float acc[16];
    #pragma unroll
    for (int d = 0; d < 16; ++d) acc[d] = 0.f;
    float lsum = 0.f;

    #pragma unroll 2
    for (int jj = 0; jj <= 128; ++jj) {
        const int j = i - 128 + jj;
        const int r = row_in + jj;               // LDS row, < 192
        const int ch0 = (2 * c4)     ^ (r & 7);
        const int ch1 = (2 * c4 + 1) ^ (r & 7);
        u16x8 k0v = *(const u16x8*)&ks[r * 64 + ch0 * 8];
        u16x8 k1v = *(const u16x8*)&ks[r * 64 + ch1 * 8];
        float s = 0.f;
        #pragma unroll
        for (int d = 0; d < 8; ++d)
            s += qf[d] * bf2f(k0v[d]) + qf[8 + d] * bf2f(k1v[d]);
        s += __shfl_xor(s, 1);
        s += __shfl_xor(s, 2);
        const float p = (j >= 0) ? __expf(fminf(s * scale, 80.f)) : 0.f;
        lsum += p;
        u16x8 v0v = *(const u16x8*)&vs[r * 64 + ch0 * 8];
        u16x8 v1v = *(const u16x8*)&vs[r * 64 + ch1 * 8];
        #pragma unroll
        for (int d = 0; d < 8; ++d) {
            acc[d]     += p * bf2f(v0v[d]);
            acc[8 + d] += p * bf2f(v1v[d]);
        }
    }

    const float inv = 1.f / lsum;
    u16x8 o0, o1;
    #pragma unroll
    for (int d = 0; d < 8; ++d) {
        o0[d] = f2bf(acc[d] * inv);
        o1[d] = f2bf(acc[8 + d] * inv);
    }
    const size_t obase = ((size_t)(b * K_ + i) * H_ + h) * 64 + c4 * 16;
    *(u16x8*)&ob[obase] = o0;
    *(u16x8*)&ob[obase + 8] = o1;
}

// ---------------------------------------------------------------------------
extern "C" void kernel_launch(void* const* d_in, const int* in_sizes, int n_in,
                              void* d_out, int out_size, void* d_ws, size_t ws_size,
                              hipStream_t stream)
{
    const float* query = (const float*)d_in[0];
    const float* key   = (const float*)d_in[1];
    const float* value = (const float*)d_in[2];
    const float* W_q   = (const float*)d_in[3];
    const float* b_q   = (const float*)d_in[4];
    const float* W_k   = (const float*)d_in[5];
    const float* b_k   = (const float*)d_in[6];
    const float* W_v   = (const float*)d_in[7];
    const float* b_v   = (const float*)d_in[8];
    const float* W_o   = (const float*)d_in[9];
    const float* b_o   = (const float*)d_in[10];
    float* out = (float*)d_out;

    // workspace layout (bf16), peak 35.7 MB (< 50.3 MB proven available):
    const size_t NX = (size_t)M_ * 512;          // 4,194,304
    const size_t NW = 512 * 512;                 // 262,144
    unsigned short* xb  = (unsigned short*)d_ws; // staging input (reused 3x)
    unsigned short* wqb = xb + NX;
    unsigned short* wkb = wqb + NW;
    unsigned short* wvb = wkb + NW;
    unsigned short* wob = wvb + NW;
    unsigned short* qp  = wob + NW;
    unsigned short* kp  = qp + NX;
    unsigned short* vp  = kp + NX;
    unsigned short* ap  = xb;                    // attn out aliases xb (dead then)

    const int NX8 = (int)(NX / 8), NW8 = (int)(NW / 8);

    // convert query + all weights; project q
    CvtA a1;
    a1.c[0] = { query, xb,  NX8 };
    a1.c[1] = { W_q,   wqb, NW8 };
    a1.c[2] = { W_k,   wkb, NW8 };
    a1.c[3] = { W_v,   wvb, NW8 };
    a1.c[4] = { W_o,   wob, NW8 };
    cvt_multi<<<dim3(256, 5), 256, 0, stream>>>(a1);
    gemm_bf16k<true><<<256, 512, 0, stream>>>(xb, wqb, b_q, qp);

    CvtA a2; a2.c[0] = { key, xb, NX8 };
    a2.c[1] = a2.c[2] = a2.c[3] = a2.c[4] = Cvt{ nullptr, nullptr, 0 };
    cvt_multi<<<dim3(256, 1), 256, 0, stream>>>(a2);
    gemm_bf16k<true><<<256, 512, 0, stream>>>(xb, wkb, b_k, kp);

    CvtA a3; a3.c[0] = { value, xb, NX8 };
    a3.c[1] = a3.c[2] = a3.c[3] = a3.c[4] = Cvt{ nullptr, nullptr, 0 };
    cvt_multi<<<dim3(256, 1), 256, 0, stream>>>(a3);
    gemm_bf16k<true><<<256, 512, 0, stream>>>(xb, wvb, b_v, vp);

    attn_local_bf16<<<dim3(K_ / 64, H_, B_), 256, 0, stream>>>(qp, kp, vp, ap);

    gemm_bf16k<false><<<256, 512, 0, stream>>>(ap, wob, b_o, out);
}

// Round 3
// 81.563 us; speedup vs baseline: 9.2649x; 1.9218x over previous
//
#include <hip/hip_runtime.h>
#include <hip/hip_bf16.h>
#include <stdint.h>

#define B_ 4
#define K_ 2048
#define D_ 512
#define H_ 8
#define ATTN_ 128
#define M_ (B_ * K_)   // 8192

typedef __attribute__((ext_vector_type(4))) float f32x4;
typedef __attribute__((ext_vector_type(8))) short bf16x8;
typedef __attribute__((ext_vector_type(8))) unsigned short u16x8;
typedef __attribute__((ext_vector_type(2))) unsigned int u32x2;

__device__ __forceinline__ unsigned short f2bf(float f) {
    union { float f; unsigned int i; } x; x.f = f;
    unsigned int r = x.i + 0x7fffu + ((x.i >> 16) & 1u);   // RNE
    return (unsigned short)(r >> 16);
}
__device__ __forceinline__ float bf2f(unsigned short u) {
    union { unsigned int i; float f; } x; x.i = ((unsigned int)u) << 16; return x.f;
}
__device__ __forceinline__ void gload_lds16(const unsigned short* g, unsigned short* l) {
    __builtin_amdgcn_global_load_lds(
        (const __attribute__((address_space(1))) void*)g,
        (__attribute__((address_space(3))) void*)l, 16, 0, 0);
}
__device__ __forceinline__ unsigned lds_addr(const void* p) {
    return (unsigned)(unsigned long long)
        (const __attribute__((address_space(3))) void*)p;
}

// ---------------------------------------------------------------------------
// fp32 -> bf16 conversion, 7 tensors in one launch (blockIdx.y = job)
// ---------------------------------------------------------------------------
struct Cvt { const float* s; unsigned short* d; int n8; };
struct CvtA { Cvt c[7]; };

__global__ __launch_bounds__(256)
void cvt_multi(CvtA a) {
    const Cvt c = a.c[blockIdx.y];
    const float4* s4 = (const float4*)c.s;
    u16x8* d8 = (u16x8*)c.d;
    for (int g = blockIdx.x * 256 + threadIdx.x; g < c.n8; g += gridDim.x * 256) {
        float4 f0 = s4[2 * g], f1 = s4[2 * g + 1];
        u16x8 o;
        o[0] = f2bf(f0.x); o[1] = f2bf(f0.y); o[2] = f2bf(f0.z); o[3] = f2bf(f0.w);
        o[4] = f2bf(f1.x); o[5] = f2bf(f1.y); o[6] = f2bf(f1.z); o[7] = f2bf(f1.w);
        d8[g] = o;
    }
}

// ---------------------------------------------------------------------------
// bf16 MFMA GEMM: C[8192,512] = A[8192,512] @ W[512,512]^T + bias
// (unchanged from round 2 — validated)
// ---------------------------------------------------------------------------
template<bool OUT_BF16>
__global__ __launch_bounds__(512)
void gemm_bf16k(const unsigned short* __restrict__ A,
                const unsigned short* __restrict__ W,
                const float* __restrict__ bias,
                void* __restrict__ C)
{
    __shared__ unsigned short As[2][128 * 64];
    __shared__ unsigned short Bs[2][128 * 64];

    const int id  = blockIdx.x;
    const int swz = (id & 7) * 32 + (id >> 3);   // XCD-contiguous (256%8==0)
    const int bm  = (swz & 63) * 128;
    const int bn  = (swz >> 6) * 128;

    const int tid = threadIdx.x;
    const int w   = tid >> 6;
    const int l   = tid & 63;
    const int lr  = l & 15;
    const int lhi = l >> 4;
    const int wm  = (w >> 1) * 32;
    const int wn  = (w & 1) * 64;

    f32x4 acc[2][4];
    #pragma unroll
    for (int i = 0; i < 2; ++i)
        #pragma unroll
        for (int j = 0; j < 4; ++j) acc[i][j] = (f32x4){0.f, 0.f, 0.f, 0.f};

    auto stage = [&](int buf, int t) {
        const int k0 = t * 64;
        #pragma unroll
        for (int it = 0; it < 2; ++it) {
            const int f  = it * 64 + l;
            const int r  = w * 16 + (f >> 3);
            const int cs = (f & 7) ^ (r & 7);
            gload_lds16(A + (size_t)(bm + r) * D_ + k0 + cs * 8,
                        &As[buf][(w * 128 + it * 64) * 8]);
        }
        #pragma unroll
        for (int it = 0; it < 2; ++it) {
            const int f  = it * 64 + l;
            const int r  = w * 16 + (f >> 3);
            const int cs = (f & 7) ^ (r & 7);
            gload_lds16(W + (size_t)(bn + r) * D_ + k0 + cs * 8,
                        &Bs[buf][(w * 128 + it * 64) * 8]);
        }
    };

    stage(0, 0);
    __syncthreads();

    int buf = 0;
    for (int t = 0; t < 8; ++t) {
        if (t < 7) stage(buf ^ 1, t + 1);
        #pragma unroll
        for (int kk = 0; kk < 2; ++kk) {
            bf16x8 af[2], bfr[4];
            #pragma unroll
            for (int fm = 0; fm < 2; ++fm) {
                const int row = wm + fm * 16 + lr;
                const int ch  = (kk * 4 + lhi) ^ (lr & 7);
                af[fm] = *(const bf16x8*)&As[buf][row * 64 + ch * 8];
            }
            #pragma unroll
            for (int fn = 0; fn < 4; ++fn) {
                const int row = wn + fn * 16 + lr;
                const int ch  = (kk * 4 + lhi) ^ (lr & 7);
                bfr[fn] = *(const bf16x8*)&Bs[buf][row * 64 + ch * 8];
            }
            #pragma unroll
            for (int fm = 0; fm < 2; ++fm)
                #pragma unroll
                for (int fn = 0; fn < 4; ++fn)
                    acc[fm][fn] = __builtin_amdgcn_mfma_f32_16x16x32_bf16(
                        af[fm], bfr[fn], acc[fm][fn], 0, 0, 0);
        }
        __syncthreads();
        buf ^= 1;
    }

    float bv[4];
    #pragma unroll
    for (int fn = 0; fn < 4; ++fn) bv[fn] = bias[bn + wn + fn * 16 + lr];

    #pragma unroll
    for (int fm = 0; fm < 2; ++fm)
        #pragma unroll
        for (int fn = 0; fn < 4; ++fn)
            #pragma unroll
            for (int rr = 0; rr < 4; ++rr) {
                const int row = bm + wm + fm * 16 + lhi * 4 + rr;
                const int col = bn + wn + fn * 16 + lr;
                const float val = acc[fm][fn][rr] + bv[fn];
                if (OUT_BF16)
                    ((unsigned short*)C)[(size_t)row * 512 + col] = f2bf(val);
                else
                    ((float*)C)[(size_t)row * 512 + col] = val;
            }
}

// ---------------------------------------------------------------------------
// MFMA banded-causal local attention.
// Block: 64 q-rows of one (b,h). 4 waves, wave w owns q rows 16w..16w+15.
// K window [192][64] staged like the GEMM (XOR-swz chunks, global_load_lds).
// V staged dv-subtiled [4][192][16], k-PERMUTED so 2x ds_read_b64_tr_b16
// deliver the exact 16x16x32 B-frag (k = 8*(l>>4)+j).
// Softmax in-register (no max-sub; scale=1/sqrt(2048)), P^ bf16 -> per-wave
// LDS strip (stride 200 shorts), PV accumulates f32, normalize at the end.
// Band exploited: 10/12 S-frags, 5/6 PV k-steps per wave (kc-aligned).
// ---------------------------------------------------------------------------
__global__ __launch_bounds__(256)
void attn_mfma(const unsigned short* __restrict__ qb,
               const unsigned short* __restrict__ kb,
               const unsigned short* __restrict__ vb,
               unsigned short* __restrict__ ob)
{
    __shared__ unsigned short Ksh[192 * 64];      // 24 KB
    __shared__ unsigned short Vsh[4 * 192 * 16];  // 24 KB
    __shared__ unsigned short Psh[4 * 16 * 200];  // 25 KB

    // XCD swizzle: 128 consecutive logical blocks (4 heads) per XCD
    const int flat = blockIdx.x + 32 * (blockIdx.y + 8 * blockIdx.z);
    const int lg   = (flat & 7) * 128 + (flat >> 3);
    const int tile = lg & 31;
    const int h    = (lg >> 5) & 7;
    const int b    = lg >> 8;

    const int i0 = tile * 64;
    const int j0 = i0 - 128;
    const int tid = threadIdx.x;
    const int w   = tid >> 6;
    const int l   = tid & 63;
    const int lr  = l & 15;
    const int lhi = l >> 4;
    const float scale = 0.0220970869120796f;      // 1/sqrt(2048)

    const size_t hbase = ((size_t)b * K_) * 512 + (size_t)h * 64;
    const unsigned short* kh = kb + hbase;
    const unsigned short* vh = vb + hbase;
    const unsigned short* qh = qb + hbase;
    unsigned short* oh = ob + hbase;

    // ---- stage K: 1536 16B-chunks, linear dest, inverse-XOR source, clamp j
    #pragma unroll
    for (int it = 0; it < 6; ++it) {
        const int cg  = it * 4 + w;               // chunk group (64 chunks)
        const int cid = cg * 64 + l;
        const int r = cid >> 3, c = cid & 7;
        const int cs = c ^ (r & 7);
        int j = j0 + r; if (j < 0) j = 0;
        gload_lds16(kh + (size_t)j * 512 + cs * 8, &Ksh[cg * 64 * 8]);
    }
    // ---- stage V: dv-subtiled, k-permuted; linear dest
    #pragma unroll
    for (int it = 0; it < 6; ++it) {
        const int cg  = it * 4 + w;
        const int cid = cg * 64 + l;
        const int blk = cid / 384;                // dv block 0..3
        const int rem = cid - blk * 384;
        const int prow = rem >> 1, hf = rem & 1;
        const int a = prow >> 2, bb = prow & 3;
        const int k = (a < 24) ? (8 * a + bb) : (8 * (a - 24) + 4 + bb);
        int j = j0 + k; if (j < 0) j = 0;
        gload_lds16(vh + (size_t)j * 512 + blk * 16 + hf * 8, &Vsh[cg * 64 * 8]);
    }

    // ---- Q A-frags straight from global (row = lr of this wave's strip)
    bf16x8 qa[2];
    {
        const unsigned short* qrow = qh + (size_t)(i0 + 16 * w + lr) * 512;
        qa[0] = *(const bf16x8*)(qrow + lhi * 8);
        qa[1] = *(const bf16x8*)(qrow + 32 + lhi * 8);
    }
    __syncthreads();   // drains vmcnt(0) for the LDS staging

    // ---- QK^T: 10 S-frags (cols [16*(w&~1), +160))
    const int jcbase = w & ~1;
    f32x4 sacc[10];
    #pragma unroll
    for (int jc = 0; jc < 10; ++jc) sacc[jc] = (f32x4){0.f, 0.f, 0.f, 0.f};

    __builtin_amdgcn_s_setprio(1);
    #pragma unroll
    for (int kk = 0; kk < 2; ++kk) {
        const int ch = (kk * 4 + lhi) ^ (lr & 7);
        #pragma unroll
        for (int jc = 0; jc < 10; ++jc) {
            const int row = (jcbase + jc) * 16 + lr;
            bf16x8 kf = *(const bf16x8*)&Ksh[row * 64 + ch * 8];
            sacc[jc] = __builtin_amdgcn_mfma_f32_16x16x32_bf16(
                qa[kk], kf, sacc[jc], 0, 0, 0);
        }
    }
    __builtin_amdgcn_s_setprio(0);

    // ---- softmax (no max-sub), write P^ bf16 to per-wave strip
    unsigned short* myP = &Psh[w * 3200];
    const int lo0 = 128 - i0;                 // jcol >= lo0 <=> j_glob >= 0
    float lsum[4] = {0.f, 0.f, 0.f, 0.f};
    #pragma unroll
    for (int jc = 0; jc < 10; ++jc) {
        const int jcol = (jcbase + jc) * 16 + lr;
        #pragma unroll
        for (int rr = 0; rr < 4; ++rr) {
            const int iloc = 16 * w + 4 * lhi + rr;
            const bool ok = (jcol >= iloc) && (jcol <= iloc + ATTN_) && (jcol >= lo0);
            const float p = ok ? __expf(fminf(sacc[jc][rr] * scale, 80.f)) : 0.f;
            lsum[rr] += p;
            myP[(4 * lhi + rr) * 200 + jcol] = f2bf(p);
        }
    }
    #pragma unroll
    for (int rr = 0; rr < 4; ++rr) {
        float s = lsum[rr];
        s += __shfl_xor(s, 1, 16);
        s += __shfl_xor(s, 2, 16);
        s += __shfl_xor(s, 4, 16);
        s += __shfl_xor(s, 8, 16);
        lsum[rr] = s;
    }

    // ---- PV: 5 k-steps, B-frags via 2x ds_read_b64_tr_b16 from permuted Vsh
    const int kcbase = w >> 1;
    f32x4 oacc[4];
    #pragma unroll
    for (int fn = 0; fn < 4; ++fn) oacc[fn] = (f32x4){0.f, 0.f, 0.f, 0.f};
    const unsigned vbase = lds_addr(&Vsh[0]) + (unsigned)(l * 8);

    for (int kc5 = 0; kc5 < 5; ++kc5) {
        const int kc = kcbase + kc5;
        bf16x8 pa = *(const bf16x8*)&myP[lr * 200 + kc * 32 + lhi * 8];
        u32x2 vlo[4], vhi[4];
        #pragma unroll
        for (int fn = 0; fn < 4; ++fn) {
            const unsigned addr = vbase + (unsigned)((fn * 3072 + kc * 256) * 2);
            asm volatile("ds_read_b64_tr_b16 %0, %1" : "=v"(vlo[fn]) : "v"(addr));
            asm volatile("ds_read_b64_tr_b16 %0, %1 offset:3072"
                         : "=v"(vhi[fn]) : "v"(addr));
        }
        asm volatile("s_waitcnt lgkmcnt(0)" ::: "memory");
        __builtin_amdgcn_sched_barrier(0);
        __builtin_amdgcn_s_setprio(1);
        #pragma unroll
        for (int fn = 0; fn < 4; ++fn) {
            union { u32x2 h[2]; bf16x8 v; } u;
            u.h[0] = vlo[fn]; u.h[1] = vhi[fn];
            oacc[fn] = __builtin_amdgcn_mfma_f32_16x16x32_bf16(
                pa, u.v, oacc[fn], 0, 0, 0);
        }
        __builtin_amdgcn_s_setprio(0);
    }

    // ---- normalize + write bf16
    float inv[4];
    #pragma unroll
    for (int rr = 0; rr < 4; ++rr) inv[rr] = 1.f / lsum[rr];
    #pragma unroll
    for (int fn = 0; fn < 4; ++fn)
        #pragma unroll
        for (int rr = 0; rr < 4; ++rr) {
            const int row = i0 + 16 * w + 4 * lhi + rr;
            oh[(size_t)row * 512 + fn * 16 + lr] = f2bf(oacc[fn][rr] * inv[rr]);
        }
}

// ---------------------------------------------------------------------------
extern "C" void kernel_launch(void* const* d_in, const int* in_sizes, int n_in,
                              void* d_out, int out_size, void* d_ws, size_t ws_size,
                              hipStream_t stream)
{
    const float* query = (const float*)d_in[0];
    const float* key   = (const float*)d_in[1];
    const float* value = (const float*)d_in[2];
    const float* W_q   = (const float*)d_in[3];
    const float* b_q   = (const float*)d_in[4];
    const float* W_k   = (const float*)d_in[5];
    const float* b_k   = (const float*)d_in[6];
    const float* W_v   = (const float*)d_in[7];
    const float* b_v   = (const float*)d_in[8];
    const float* W_o   = (const float*)d_in[9];
    const float* b_o   = (const float*)d_in[10];
    float* out = (float*)d_out;

    // bf16 workspace, 43 MB peak:
    const size_t NX = (size_t)M_ * 512;
    const size_t NW = 512 * 512;
    unsigned short* xq  = (unsigned short*)d_ws;
    unsigned short* xk  = xq + NX;
    unsigned short* xv  = xk + NX;
    unsigned short* wqb = xv + NX;
    unsigned short* wkb = wqb + NW;
    unsigned short* wvb = wkb + NW;
    unsigned short* wob = wvb + NW;
    unsigned short* qp  = wob + NW;
    unsigned short* kp  = qp + NX;
    unsigned short* vp  = xq;          // aliases xq (dead after GEMM 1)
    unsigned short* ap  = xk;          // aliases xk (dead after GEMM 2)

    const int NX8 = (int)(NX / 8), NW8 = (int)(NW / 8);

    CvtA a;
    a.c[0] = { query, xq,  NX8 };
    a.c[1] = { key,   xk,  NX8 };
    a.c[2] = { value, xv,  NX8 };
    a.c[3] = { W_q,   wqb, NW8 };
    a.c[4] = { W_k,   wkb, NW8 };
    a.c[5] = { W_v,   wvb, NW8 };
    a.c[6] = { W_o,   wob, NW8 };
    cvt_multi<<<dim3(256, 7), 256, 0, stream>>>(a);

    gemm_bf16k<true><<<256, 512, 0, stream>>>(xq, wqb, b_q, qp);
    gemm_bf16k<true><<<256, 512, 0, stream>>>(xk, wkb, b_k, kp);
    gemm_bf16k<true><<<256, 512, 0, stream>>>(xv, wvb, b_v, vp);

    attn_mfma<<<dim3(32, 8, 4), 256, 0, stream>>>(qp, kp, vp, ap);

    gemm_bf16k<false><<<256, 512, 0, stream>>>(ap, wob, b_o, out);
}

// Round 4
// 62.492 us; speedup vs baseline: 12.0924x; 1.3052x over previous
//
#include <hip/hip_runtime.h>
#include <hip/hip_bf16.h>
#include <stdint.h>

#define B_ 4
#define K_ 2048
#define D_ 512
#define H_ 8
#define ATTN_ 128
#define M_ (B_ * K_)   // 8192

typedef __attribute__((ext_vector_type(4))) float f32x4;
typedef __attribute__((ext_vector_type(8))) short bf16x8;
typedef __attribute__((ext_vector_type(8))) unsigned short u16x8;
typedef __attribute__((ext_vector_type(2))) unsigned int u32x2;

__device__ __forceinline__ unsigned short f2bf(float f) {
    union { float f; unsigned int i; } x; x.f = f;
    unsigned int r = x.i + 0x7fffu + ((x.i >> 16) & 1u);   // RNE
    return (unsigned short)(r >> 16);
}
__device__ __forceinline__ float bf2f(unsigned short u) {
    union { unsigned int i; float f; } x; x.i = ((unsigned int)u) << 16; return x.f;
}
__device__ __forceinline__ void gload_lds16(const unsigned short* g, unsigned short* l) {
    __builtin_amdgcn_global_load_lds(
        (const __attribute__((address_space(1))) void*)g,
        (__attribute__((address_space(3))) void*)l, 16, 0, 0);
}
__device__ __forceinline__ unsigned lds_addr(const void* p) {
    return (unsigned)(unsigned long long)
        (const __attribute__((address_space(3))) void*)p;
}

// ---------------------------------------------------------------------------
// fp32 -> bf16 conversion: weights only now (4 tensors)
// ---------------------------------------------------------------------------
struct Cvt { const float* s; unsigned short* d; int n8; };
struct CvtA { Cvt c[4]; };

__global__ __launch_bounds__(256)
void cvt_multi(CvtA a) {
    const Cvt c = a.c[blockIdx.y];
    const float4* s4 = (const float4*)c.s;
    u16x8* d8 = (u16x8*)c.d;
    for (int g = blockIdx.x * 256 + threadIdx.x; g < c.n8; g += gridDim.x * 256) {
        float4 f0 = s4[2 * g], f1 = s4[2 * g + 1];
        u16x8 o;
        o[0] = f2bf(f0.x); o[1] = f2bf(f0.y); o[2] = f2bf(f0.z); o[3] = f2bf(f0.w);
        o[4] = f2bf(f1.x); o[5] = f2bf(f1.y); o[6] = f2bf(f1.z); o[7] = f2bf(f1.w);
        d8[g] = o;
    }
}

// ---------------------------------------------------------------------------
// Batched QKV GEMM: for z in {q,k,v}: C_z[8192,512] = A_z(fp32) @ W_z^T + b_z
// A converted fp32->bf16 inline during staging (T14 split: load early,
// cvt+ds_write late). Linear LDS layout slot s holds logical chunk s^(r&7)
// (permutation on the LOAD side for both A and W -> conflict-free writes,
// 2-way-max reads). Tile 128x128, BK=64, 512 thr, grid (256, 3) ->
// 2 blocks/CU co-resident (64 KB LDS) so barrier drains overlap.
// ---------------------------------------------------------------------------
struct QkvArgs {
    const float* A[3];
    const unsigned short* Wt[3];
    const float* bias[3];
    unsigned short* C[3];
};

__global__ __launch_bounds__(512, 4)
void gemm_qkv(QkvArgs args)
{
    __shared__ unsigned short As[2][128 * 64];   // 32 KB
    __shared__ unsigned short Bs[2][128 * 64];   // 32 KB

    const int z = blockIdx.y;
    const float* Az = args.A[z];
    const unsigned short* Wz = args.Wt[z];
    const float* biz = args.bias[z];
    unsigned short* Cz = args.C[z];

    const int id  = blockIdx.x;                  // 256 blocks: 64m x 4n
    const int swz = (id & 7) * 32 + (id >> 3);   // XCD c -> m in [8c,8c+8), all n
    const int bm  = (swz >> 2) * 128;
    const int bn  = (swz & 3) * 128;

    const int tid = threadIdx.x;
    const int w   = tid >> 6;
    const int l   = tid & 63;
    const int lr  = l & 15;
    const int lhi = l >> 4;
    const int wm  = (w >> 1) * 32;
    const int wn  = (w & 1) * 64;

    f32x4 acc[2][4];
    #pragma unroll
    for (int i = 0; i < 2; ++i)
        #pragma unroll
        for (int j = 0; j < 4; ++j) acc[i][j] = (f32x4){0.f, 0.f, 0.f, 0.f};

    // A: 1024 chunks (128 rows x 8), 2 per thread. Linear dest slot cid;
    // logical K-chunk c = (cid&7) ^ (r&7) fetched from global.
    float4 fa[2][2];
    auto loadA = [&](int t) {
        const int k0 = t * 64;
        #pragma unroll
        for (int it = 0; it < 2; ++it) {
            const int cid = it * 512 + tid;
            const int r = cid >> 3;
            const int c = (cid & 7) ^ (r & 7);
            const float* src = Az + (size_t)(bm + r) * D_ + k0 + c * 8;
            fa[it][0] = *(const float4*)src;
            fa[it][1] = *(const float4*)(src + 4);
        }
    };
    auto writeA = [&](int buf) {
        #pragma unroll
        for (int it = 0; it < 2; ++it) {
            const int cid = it * 512 + tid;
            u16x8 o;
            o[0] = f2bf(fa[it][0].x); o[1] = f2bf(fa[it][0].y);
            o[2] = f2bf(fa[it][0].z); o[3] = f2bf(fa[it][0].w);
            o[4] = f2bf(fa[it][1].x); o[5] = f2bf(fa[it][1].y);
            o[6] = f2bf(fa[it][1].z); o[7] = f2bf(fa[it][1].w);
            *(u16x8*)&As[buf][cid * 8] = o;      // linear: conflict-free
        }
    };
    auto stageB = [&](int buf, int t) {
        const int k0 = t * 64;
        #pragma unroll
        for (int it = 0; it < 2; ++it) {
            const int f  = it * 64 + l;
            const int r  = w * 16 + (f >> 3);
            const int cs = (f & 7) ^ (r & 7);
            gload_lds16(Wz + (size_t)(bn + r) * D_ + k0 + cs * 8,
                        &Bs[buf][(w * 128 + it * 64) * 8]);
        }
    };

    loadA(0); writeA(0);
    stageB(0, 0);
    __syncthreads();

    int buf = 0;
    for (int t = 0; t < 8; ++t) {                // K = 512 = 8 x 64
        if (t < 7) { loadA(t + 1); stageB(buf ^ 1, t + 1); }
        #pragma unroll
        for (int kk = 0; kk < 2; ++kk) {
            bf16x8 af[2], bfr[4];
            #pragma unroll
            for (int fm = 0; fm < 2; ++fm) {
                const int row = wm + fm * 16 + lr;
                const int ch  = (kk * 4 + lhi) ^ (lr & 7);
                af[fm] = *(const bf16x8*)&As[buf][row * 64 + ch * 8];
            }
            #pragma unroll
            for (int fn = 0; fn < 4; ++fn) {
                const int row = wn + fn * 16 + lr;
                const int ch  = (kk * 4 + lhi) ^ (lr & 7);
                bfr[fn] = *(const bf16x8*)&Bs[buf][row * 64 + ch * 8];
            }
            #pragma unroll
            for (int fm = 0; fm < 2; ++fm)
                #pragma unroll
                for (int fn = 0; fn < 4; ++fn)
                    acc[fm][fn] = __builtin_amdgcn_mfma_f32_16x16x32_bf16(
                        af[fm], bfr[fn], acc[fm][fn], 0, 0, 0);
        }
        if (t < 7) writeA(buf ^ 1);              // vmcnt wait auto-inserted
        __syncthreads();
        buf ^= 1;
    }

    float bv[4];
    #pragma unroll
    for (int fn = 0; fn < 4; ++fn) bv[fn] = biz[bn + wn + fn * 16 + lr];

    #pragma unroll
    for (int fm = 0; fm < 2; ++fm)
        #pragma unroll
        for (int fn = 0; fn < 4; ++fn)
            #pragma unroll
            for (int rr = 0; rr < 4; ++rr) {
                const int row = bm + wm + fm * 16 + lhi * 4 + rr;
                const int col = bn + wn + fn * 16 + lr;
                Cz[(size_t)row * 512 + col] = f2bf(acc[fm][fn][rr] + bv[fn]);
            }
}

// ---------------------------------------------------------------------------
// bf16 MFMA GEMM (round-2 validated) — used for the output projection only.
// ---------------------------------------------------------------------------
template<bool OUT_BF16>
__global__ __launch_bounds__(512)
void gemm_bf16k(const unsigned short* __restrict__ A,
                const unsigned short* __restrict__ W,
                const float* __restrict__ bias,
                void* __restrict__ C)
{
    __shared__ unsigned short As[2][128 * 64];
    __shared__ unsigned short Bs[2][128 * 64];

    const int id  = blockIdx.x;
    const int swz = (id & 7) * 32 + (id >> 3);
    const int bm  = (swz & 63) * 128;
    const int bn  = (swz >> 6) * 128;

    const int tid = threadIdx.x;
    const int w   = tid >> 6;
    const int l   = tid & 63;
    const int lr  = l & 15;
    const int lhi = l >> 4;
    const int wm  = (w >> 1) * 32;
    const int wn  = (w & 1) * 64;

    f32x4 acc[2][4];
    #pragma unroll
    for (int i = 0; i < 2; ++i)
        #pragma unroll
        for (int j = 0; j < 4; ++j) acc[i][j] = (f32x4){0.f, 0.f, 0.f, 0.f};

    auto stage = [&](int buf, int t) {
        const int k0 = t * 64;
        #pragma unroll
        for (int it = 0; it < 2; ++it) {
            const int f  = it * 64 + l;
            const int r  = w * 16 + (f >> 3);
            const int cs = (f & 7) ^ (r & 7);
            gload_lds16(A + (size_t)(bm + r) * D_ + k0 + cs * 8,
                        &As[buf][(w * 128 + it * 64) * 8]);
        }
        #pragma unroll
        for (int it = 0; it < 2; ++it) {
            const int f  = it * 64 + l;
            const int r  = w * 16 + (f >> 3);
            const int cs = (f & 7) ^ (r & 7);
            gload_lds16(W + (size_t)(bn + r) * D_ + k0 + cs * 8,
                        &Bs[buf][(w * 128 + it * 64) * 8]);
        }
    };

    stage(0, 0);
    __syncthreads();

    int buf = 0;
    for (int t = 0; t < 8; ++t) {
        if (t < 7) stage(buf ^ 1, t + 1);
        #pragma unroll
        for (int kk = 0; kk < 2; ++kk) {
            bf16x8 af[2], bfr[4];
            #pragma unroll
            for (int fm = 0; fm < 2; ++fm) {
                const int row = wm + fm * 16 + lr;
                const int ch  = (kk * 4 + lhi) ^ (lr & 7);
                af[fm] = *(const bf16x8*)&As[buf][row * 64 + ch * 8];
            }
            #pragma unroll
            for (int fn = 0; fn < 4; ++fn) {
                const int row = wn + fn * 16 + lr;
                const int ch  = (kk * 4 + lhi) ^ (lr & 7);
                bfr[fn] = *(const bf16x8*)&Bs[buf][row * 64 + ch * 8];
            }
            #pragma unroll
            for (int fm = 0; fm < 2; ++fm)
                #pragma unroll
                for (int fn = 0; fn < 4; ++fn)
                    acc[fm][fn] = __builtin_amdgcn_mfma_f32_16x16x32_bf16(
                        af[fm], bfr[fn], acc[fm][fn], 0, 0, 0);
        }
        __syncthreads();
        buf ^= 1;
    }

    float bv[4];
    #pragma unroll
    for (int fn = 0; fn < 4; ++fn) bv[fn] = bias[bn + wn + fn * 16 + lr];

    #pragma unroll
    for (int fm = 0; fm < 2; ++fm)
        #pragma unroll
        for (int fn = 0; fn < 4; ++fn)
            #pragma unroll
            for (int rr = 0; rr < 4; ++rr) {
                const int row = bm + wm + fm * 16 + lhi * 4 + rr;
                const int col = bn + wn + fn * 16 + lr;
                const float val = acc[fm][fn][rr] + bv[fn];
                if (OUT_BF16)
                    ((unsigned short*)C)[(size_t)row * 512 + col] = f2bf(val);
                else
                    ((float*)C)[(size_t)row * 512 + col] = val;
            }
}

// ---------------------------------------------------------------------------
// MFMA banded-causal local attention (round-3 validated, unchanged).
// ---------------------------------------------------------------------------
__global__ __launch_bounds__(256)
void attn_mfma(const unsigned short* __restrict__ qb,
               const unsigned short* __restrict__ kb,
               const unsigned short* __restrict__ vb,
               unsigned short* __restrict__ ob)
{
    __shared__ unsigned short Ksh[192 * 64];
    __shared__ unsigned short Vsh[4 * 192 * 16];
    __shared__ unsigned short Psh[4 * 16 * 200];

    const int flat = blockIdx.x + 32 * (blockIdx.y + 8 * blockIdx.z);
    const int lg   = (flat & 7) * 128 + (flat >> 3);
    const int tile = lg & 31;
    const int h    = (lg >> 5) & 7;
    const int b    = lg >> 8;

    const int i0 = tile * 64;
    const int j0 = i0 - 128;
    const int tid = threadIdx.x;
    const int w   = tid >> 6;
    const int l   = tid & 63;
    const int lr  = l & 15;
    const int lhi = l >> 4;
    const float scale = 0.0220970869120796f;

    const size_t hbase = ((size_t)b * K_) * 512 + (size_t)h * 64;
    const unsigned short* kh = kb + hbase;
    const unsigned short* vh = vb + hbase;
    const unsigned short* qh = qb + hbase;
    unsigned short* oh = ob + hbase;

    #pragma unroll
    for (int it = 0; it < 6; ++it) {
        const int cg  = it * 4 + w;
        const int cid = cg * 64 + l;
        const int r = cid >> 3, c = cid & 7;
        const int cs = c ^ (r & 7);
        int j = j0 + r; if (j < 0) j = 0;
        gload_lds16(kh + (size_t)j * 512 + cs * 8, &Ksh[cg * 64 * 8]);
    }
    #pragma unroll
    for (int it = 0; it < 6; ++it) {
        const int cg  = it * 4 + w;
        const int cid = cg * 64 + l;
        const int blk = cid / 384;
        const int rem = cid - blk * 384;
        const int prow = rem >> 1, hf = rem & 1;
        const int a = prow >> 2, bb = prow & 3;
        const int k = (a < 24) ? (8 * a + bb) : (8 * (a - 24) + 4 + bb);
        int j = j0 + k; if (j < 0) j = 0;
        gload_lds16(vh + (size_t)j * 512 + blk * 16 + hf * 8, &Vsh[cg * 64 * 8]);
    }

    bf16x8 qa[2];
    {
        const unsigned short* qrow = qh + (size_t)(i0 + 16 * w + lr) * 512;
        qa[0] = *(const bf16x8*)(qrow + lhi * 8);
        qa[1] = *(const bf16x8*)(qrow + 32 + lhi * 8);
    }
    __syncthreads();

    const int jcbase = w & ~1;
    f32x4 sacc[10];
    #pragma unroll
    for (int jc = 0; jc < 10; ++jc) sacc[jc] = (f32x4){0.f, 0.f, 0.f, 0.f};

    __builtin_amdgcn_s_setprio(1);
    #pragma unroll
    for (int kk = 0; kk < 2; ++kk) {
        const int ch = (kk * 4 + lhi) ^ (lr & 7);
        #pragma unroll
        for (int jc = 0; jc < 10; ++jc) {
            const int row = (jcbase + jc) * 16 + lr;
            bf16x8 kf = *(const bf16x8*)&Ksh[row * 64 + ch * 8];
            sacc[jc] = __builtin_amdgcn_mfma_f32_16x16x32_bf16(
                qa[kk], kf, sacc[jc], 0, 0, 0);
        }
    }
    __builtin_amdgcn_s_setprio(0);

    unsigned short* myP = &Psh[w * 3200];
    const int lo0 = 128 - i0;
    float lsum[4] = {0.f, 0.f, 0.f, 0.f};
    #pragma unroll
    for (int jc = 0; jc < 10; ++jc) {
        const int jcol = (jcbase + jc) * 16 + lr;
        #pragma unroll
        for (int rr = 0; rr < 4; ++rr) {
            const int iloc = 16 * w + 4 * lhi + rr;
            const bool ok = (jcol >= iloc) && (jcol <= iloc + ATTN_) && (jcol >= lo0);
            const float p = ok ? __expf(fminf(sacc[jc][rr] * scale, 80.f)) : 0.f;
            lsum[rr] += p;
            myP[(4 * lhi + rr) * 200 + jcol] = f2bf(p);
        }
    }
    #pragma unroll
    for (int rr = 0; rr < 4; ++rr) {
        float s = lsum[rr];
        s += __shfl_xor(s, 1, 16);
        s += __shfl_xor(s, 2, 16);
        s += __shfl_xor(s, 4, 16);
        s += __shfl_xor(s, 8, 16);
        lsum[rr] = s;
    }

    const int kcbase = w >> 1;
    f32x4 oacc[4];
    #pragma unroll
    for (int fn = 0; fn < 4; ++fn) oacc[fn] = (f32x4){0.f, 0.f, 0.f, 0.f};
    const unsigned vbase = lds_addr(&Vsh[0]) + (unsigned)(l * 8);

    for (int kc5 = 0; kc5 < 5; ++kc5) {
        const int kc = kcbase + kc5;
        bf16x8 pa = *(const bf16x8*)&myP[lr * 200 + kc * 32 + lhi * 8];
        u32x2 vlo[4], vhi[4];
        #pragma unroll
        for (int fn = 0; fn < 4; ++fn) {
            const unsigned addr = vbase + (unsigned)((fn * 3072 + kc * 256) * 2);
            asm volatile("ds_read_b64_tr_b16 %0, %1" : "=v"(vlo[fn]) : "v"(addr));
            asm volatile("ds_read_b64_tr_b16 %0, %1 offset:3072"
                         : "=v"(vhi[fn]) : "v"(addr));
        }
        asm volatile("s_waitcnt lgkmcnt(0)" ::: "memory");
        __builtin_amdgcn_sched_barrier(0);
        __builtin_amdgcn_s_setprio(1);
        #pragma unroll
        for (int fn = 0; fn < 4; ++fn) {
            union { u32x2 h[2]; bf16x8 v; } u;
            u.h[0] = vlo[fn]; u.h[1] = vhi[fn];
            oacc[fn] = __builtin_amdgcn_mfma_f32_16x16x32_bf16(
                pa, u.v, oacc[fn], 0, 0, 0);
        }
        __builtin_amdgcn_s_setprio(0);
    }

    float inv[4];
    #pragma unroll
    for (int rr = 0; rr < 4; ++rr) inv[rr] = 1.f / lsum[rr];
    #pragma unroll
    for (int fn = 0; fn < 4; ++fn)
        #pragma unroll
        for (int rr = 0; rr < 4; ++rr) {
            const int row = i0 + 16 * w + 4 * lhi + rr;
            oh[(size_t)row * 512 + fn * 16 + lr] = f2bf(oacc[fn][rr] * inv[rr]);
        }
}

// ---------------------------------------------------------------------------
extern "C" void kernel_launch(void* const* d_in, const int* in_sizes, int n_in,
                              void* d_out, int out_size, void* d_ws, size_t ws_size,
                              hipStream_t stream)
{
    const float* query = (const float*)d_in[0];
    const float* key   = (const float*)d_in[1];
    const float* value = (const float*)d_in[2];
    const float* W_q   = (const float*)d_in[3];
    const float* b_q   = (const float*)d_in[4];
    const float* W_k   = (const float*)d_in[5];
    const float* b_k   = (const float*)d_in[6];
    const float* W_v   = (const float*)d_in[7];
    const float* b_v   = (const float*)d_in[8];
    const float* W_o   = (const float*)d_in[9];
    const float* b_o   = (const float*)d_in[10];
    float* out = (float*)d_out;

    // bf16 workspace, ~35.6 MB:
    const size_t NX = (size_t)M_ * 512;
    const size_t NW = 512 * 512;
    unsigned short* wqb = (unsigned short*)d_ws;
    unsigned short* wkb = wqb + NW;
    unsigned short* wvb = wkb + NW;
    unsigned short* wob = wvb + NW;
    unsigned short* qp  = wob + NW;
    unsigned short* kp  = qp + NX;
    unsigned short* vp  = kp + NX;
    unsigned short* ap  = vp + NX;

    const int NW8 = (int)(NW / 8);

    CvtA a;
    a.c[0] = { W_q, wqb, NW8 };
    a.c[1] = { W_k, wkb, NW8 };
    a.c[2] = { W_v, wvb, NW8 };
    a.c[3] = { W_o, wob, NW8 };
    cvt_multi<<<dim3(32, 4), 256, 0, stream>>>(a);

    QkvArgs qa;
    qa.A[0] = query; qa.A[1] = key; qa.A[2] = value;
    qa.Wt[0] = wqb;  qa.Wt[1] = wkb; qa.Wt[2] = wvb;
    qa.bias[0] = b_q; qa.bias[1] = b_k; qa.bias[2] = b_v;
    qa.C[0] = qp; qa.C[1] = kp; qa.C[2] = vp;
    gemm_qkv<<<dim3(256, 3), 512, 0, stream>>>(qa);

    attn_mfma<<<dim3(32, 8, 4), 256, 0, stream>>>(qp, kp, vp, ap);

    gemm_bf16k<false><<<256, 512, 0, stream>>>(ap, wob, b_o, out);
}

// Round 5
// 60.867 us; speedup vs baseline: 12.4151x; 1.0267x over previous
//
#include <hip/hip_runtime.h>
#include <hip/hip_bf16.h>
#include <stdint.h>

#define B_ 4
#define K_ 2048
#define D_ 512
#define H_ 8
#define ATTN_ 128
#define M_ (B_ * K_)   // 8192

typedef __attribute__((ext_vector_type(4))) float f32x4;
typedef __attribute__((ext_vector_type(8))) short bf16x8;
typedef __attribute__((ext_vector_type(8))) unsigned short u16x8;
typedef __attribute__((ext_vector_type(2))) unsigned int u32x2;

__device__ __forceinline__ unsigned short f2bf(float f) {
    union { float f; unsigned int i; } x; x.f = f;
    unsigned int r = x.i + 0x7fffu + ((x.i >> 16) & 1u);   // RNE
    return (unsigned short)(r >> 16);
}
__device__ __forceinline__ float bf2f(unsigned short u) {
    union { unsigned int i; float f; } x; x.i = ((unsigned int)u) << 16; return x.f;
}
__device__ __forceinline__ void gload_lds16(const unsigned short* g, unsigned short* l) {
    __builtin_amdgcn_global_load_lds(
        (const __attribute__((address_space(1))) void*)g,
        (__attribute__((address_space(3))) void*)l, 16, 0, 0);
}
__device__ __forceinline__ unsigned lds_addr(const void* p) {
    return (unsigned)(unsigned long long)
        (const __attribute__((address_space(3))) void*)p;
}

// ---------------------------------------------------------------------------
// fp32 -> bf16 conversion: weights only (4 tensors)
// ---------------------------------------------------------------------------
struct Cvt { const float* s; unsigned short* d; int n8; };
struct CvtA { Cvt c[4]; };

__global__ __launch_bounds__(256)
void cvt_multi(CvtA a) {
    const Cvt c = a.c[blockIdx.y];
    const float4* s4 = (const float4*)c.s;
    u16x8* d8 = (u16x8*)c.d;
    for (int g = blockIdx.x * 256 + threadIdx.x; g < c.n8; g += gridDim.x * 256) {
        float4 f0 = s4[2 * g], f1 = s4[2 * g + 1];
        u16x8 o;
        o[0] = f2bf(f0.x); o[1] = f2bf(f0.y); o[2] = f2bf(f0.z); o[3] = f2bf(f0.w);
        o[4] = f2bf(f1.x); o[5] = f2bf(f1.y); o[6] = f2bf(f1.z); o[7] = f2bf(f1.w);
        d8[g] = o;
    }
}

// ---------------------------------------------------------------------------
// Batched QKV GEMM with 2-DEEP A-prefetch pipeline.
// for z in {q,k,v}: C_z[8192,512] = A_z(fp32->bf16 inline) @ W_z^T + b_z.
// Step t: issue loadA(t+2) into reg-set (t+1)&1; MFMA on buf t&1;
// writeA(tile t+1 from reg-set t&1) AFTER the MFMA cluster (sched_barrier
// pins it) -> A-load latency budget >= 1 full K-step (~1000+ cyc).
// K-loop fully unrolled so reg-set indices are static (no scratch).
// ---------------------------------------------------------------------------
struct QkvArgs {
    const float* A[3];
    const unsigned short* Wt[3];
    const float* bias[3];
    unsigned short* C[3];
};

__global__ __launch_bounds__(512, 4)
void gemm_qkv(QkvArgs args)
{
    __shared__ unsigned short As[2][128 * 64];   // 32 KB
    __shared__ unsigned short Bs[2][128 * 64];   // 32 KB

    const int z = blockIdx.y;
    const float* Az = args.A[z];
    const unsigned short* Wz = args.Wt[z];
    const float* biz = args.bias[z];
    unsigned short* Cz = args.C[z];

    const int id  = blockIdx.x;                  // 256 blocks: 64m x 4n
    const int swz = (id & 7) * 32 + (id >> 3);   // XCD c -> m in [8c,8c+8)
    const int bm  = (swz >> 2) * 128;
    const int bn  = (swz & 3) * 128;

    const int tid = threadIdx.x;
    const int w   = tid >> 6;
    const int l   = tid & 63;
    const int lr  = l & 15;
    const int lhi = l >> 4;
    const int wm  = (w >> 1) * 32;
    const int wn  = (w & 1) * 64;

    f32x4 acc[2][4];
    #pragma unroll
    for (int i = 0; i < 2; ++i)
        #pragma unroll
        for (int j = 0; j < 4; ++j) acc[i][j] = (f32x4){0.f, 0.f, 0.f, 0.f};

    // Two register sets for in-flight A tiles (static-indexed after unroll).
    float4 fa[2][2][2];   // [set][it][half]

    auto loadA = [&](int t, int s) {
        const int k0 = t * 64;
        #pragma unroll
        for (int it = 0; it < 2; ++it) {
            const int cid = it * 512 + tid;
            const int r = cid >> 3;
            const int c = (cid & 7) ^ (r & 7);   // load-side XOR permutation
            const float* src = Az + (size_t)(bm + r) * D_ + k0 + c * 8;
            fa[s][it][0] = *(const float4*)src;
            fa[s][it][1] = *(const float4*)(src + 4);
        }
    };
    auto writeA = [&](int buf, int s) {
        #pragma unroll
        for (int it = 0; it < 2; ++it) {
            const int cid = it * 512 + tid;
            u16x8 o;
            o[0] = f2bf(fa[s][it][0].x); o[1] = f2bf(fa[s][it][0].y);
            o[2] = f2bf(fa[s][it][0].z); o[3] = f2bf(fa[s][it][0].w);
            o[4] = f2bf(fa[s][it][1].x); o[5] = f2bf(fa[s][it][1].y);
            o[6] = f2bf(fa[s][it][1].z); o[7] = f2bf(fa[s][it][1].w);
            *(u16x8*)&As[buf][cid * 8] = o;      // linear dest: conflict-free
        }
    };
    auto stageB = [&](int buf, int t) {
        const int k0 = t * 64;
        #pragma unroll
        for (int it = 0; it < 2; ++it) {
            const int f  = it * 64 + l;
            const int r  = w * 16 + (f >> 3);
            const int cs = (f & 7) ^ (r & 7);
            gload_lds16(Wz + (size_t)(bn + r) * D_ + k0 + cs * 8,
                        &Bs[buf][(w * 128 + it * 64) * 8]);
        }
    };

    // Prologue: tile0 -> LDS buf0; tile1 loads in flight in reg-set 0.
    loadA(0, 0);
    writeA(0, 0);
    loadA(1, 0);
    stageB(0, 0);
    __syncthreads();

    #pragma unroll
    for (int t = 0; t < 8; ++t) {                // K = 512 = 8 x 64
        const int buf = t & 1;                   // tile t lives in buffer t&1
        if (t < 7) stageB(buf ^ 1, t + 1);       // async B prefetch
        if (t < 6) loadA(t + 2, (t + 1) & 1);    // issue A loads 2 tiles ahead
        #pragma unroll
        for (int kk = 0; kk < 2; ++kk) {
            bf16x8 af[2], bfr[4];
            #pragma unroll
            for (int fm = 0; fm < 2; ++fm) {
                const int row = wm + fm * 16 + lr;
                const int ch  = (kk * 4 + lhi) ^ (lr & 7);
                af[fm] = *(const bf16x8*)&As[buf][row * 64 + ch * 8];
            }
            #pragma unroll
            for (int fn = 0; fn < 4; ++fn) {
                const int row = wn + fn * 16 + lr;
                const int ch  = (kk * 4 + lhi) ^ (lr & 7);
                bfr[fn] = *(const bf16x8*)&Bs[buf][row * 64 + ch * 8];
            }
            #pragma unroll
            for (int fm = 0; fm < 2; ++fm)
                #pragma unroll
                for (int fn = 0; fn < 4; ++fn)
                    acc[fm][fn] = __builtin_amdgcn_mfma_f32_16x16x32_bf16(
                        af[fm], bfr[fn], acc[fm][fn], 0, 0, 0);
        }
        __builtin_amdgcn_sched_barrier(0);       // keep writeA's wait below MFMA
        if (t < 7) {
            writeA(buf ^ 1, t & 1);              // tile t+1 (issued at t-1)
            __syncthreads();
        }
    }

    float bv[4];
    #pragma unroll
    for (int fn = 0; fn < 4; ++fn) bv[fn] = biz[bn + wn + fn * 16 + lr];

    #pragma unroll
    for (int fm = 0; fm < 2; ++fm)
        #pragma unroll
        for (int fn = 0; fn < 4; ++fn)
            #pragma unroll
            for (int rr = 0; rr < 4; ++rr) {
                const int row = bm + wm + fm * 16 + lhi * 4 + rr;
                const int col = bn + wn + fn * 16 + lr;
                Cz[(size_t)row * 512 + col] = f2bf(acc[fm][fn][rr] + bv[fn]);
            }
}

// ---------------------------------------------------------------------------
// bf16 MFMA GEMM (round-2 validated) — output projection only.
// ---------------------------------------------------------------------------
template<bool OUT_BF16>
__global__ __launch_bounds__(512)
void gemm_bf16k(const unsigned short* __restrict__ A,
                const unsigned short* __restrict__ W,
                const float* __restrict__ bias,
                void* __restrict__ C)
{
    __shared__ unsigned short As[2][128 * 64];
    __shared__ unsigned short Bs[2][128 * 64];

    const int id  = blockIdx.x;
    const int swz = (id & 7) * 32 + (id >> 3);
    const int bm  = (swz & 63) * 128;
    const int bn  = (swz >> 6) * 128;

    const int tid = threadIdx.x;
    const int w   = tid >> 6;
    const int l   = tid & 63;
    const int lr  = l & 15;
    const int lhi = l >> 4;
    const int wm  = (w >> 1) * 32;
    const int wn  = (w & 1) * 64;

    f32x4 acc[2][4];
    #pragma unroll
    for (int i = 0; i < 2; ++i)
        #pragma unroll
        for (int j = 0; j < 4; ++j) acc[i][j] = (f32x4){0.f, 0.f, 0.f, 0.f};

    auto stage = [&](int buf, int t) {
        const int k0 = t * 64;
        #pragma unroll
        for (int it = 0; it < 2; ++it) {
            const int f  = it * 64 + l;
            const int r  = w * 16 + (f >> 3);
            const int cs = (f & 7) ^ (r & 7);
            gload_lds16(A + (size_t)(bm + r) * D_ + k0 + cs * 8,
                        &As[buf][(w * 128 + it * 64) * 8]);
        }
        #pragma unroll
        for (int it = 0; it < 2; ++it) {
            const int f  = it * 64 + l;
            const int r  = w * 16 + (f >> 3);
            const int cs = (f & 7) ^ (r & 7);
            gload_lds16(W + (size_t)(bn + r) * D_ + k0 + cs * 8,
                        &Bs[buf][(w * 128 + it * 64) * 8]);
        }
    };

    stage(0, 0);
    __syncthreads();

    int buf = 0;
    for (int t = 0; t < 8; ++t) {
        if (t < 7) stage(buf ^ 1, t + 1);
        #pragma unroll
        for (int kk = 0; kk < 2; ++kk) {
            bf16x8 af[2], bfr[4];
            #pragma unroll
            for (int fm = 0; fm < 2; ++fm) {
                const int row = wm + fm * 16 + lr;
                const int ch  = (kk * 4 + lhi) ^ (lr & 7);
                af[fm] = *(const bf16x8*)&As[buf][row * 64 + ch * 8];
            }
            #pragma unroll
            for (int fn = 0; fn < 4; ++fn) {
                const int row = wn + fn * 16 + lr;
                const int ch  = (kk * 4 + lhi) ^ (lr & 7);
                bfr[fn] = *(const bf16x8*)&Bs[buf][row * 64 + ch * 8];
            }
            #pragma unroll
            for (int fm = 0; fm < 2; ++fm)
                #pragma unroll
                for (int fn = 0; fn < 4; ++fn)
                    acc[fm][fn] = __builtin_amdgcn_mfma_f32_16x16x32_bf16(
                        af[fm], bfr[fn], acc[fm][fn], 0, 0, 0);
        }
        __syncthreads();
        buf ^= 1;
    }

    float bv[4];
    #pragma unroll
    for (int fn = 0; fn < 4; ++fn) bv[fn] = bias[bn + wn + fn * 16 + lr];

    #pragma unroll
    for (int fm = 0; fm < 2; ++fm)
        #pragma unroll
        for (int fn = 0; fn < 4; ++fn)
            #pragma unroll
            for (int rr = 0; rr < 4; ++rr) {
                const int row = bm + wm + fm * 16 + lhi * 4 + rr;
                const int col = bn + wn + fn * 16 + lr;
                const float val = acc[fm][fn][rr] + bv[fn];
                if (OUT_BF16)
                    ((unsigned short*)C)[(size_t)row * 512 + col] = f2bf(val);
                else
                    ((float*)C)[(size_t)row * 512 + col] = val;
            }
}

// ---------------------------------------------------------------------------
// MFMA banded-causal local attention (round-3 validated, unchanged).
// ---------------------------------------------------------------------------
__global__ __launch_bounds__(256)
void attn_mfma(const unsigned short* __restrict__ qb,
               const unsigned short* __restrict__ kb,
               const unsigned short* __restrict__ vb,
               unsigned short* __restrict__ ob)
{
    __shared__ unsigned short Ksh[192 * 64];
    __shared__ unsigned short Vsh[4 * 192 * 16];
    __shared__ unsigned short Psh[4 * 16 * 200];

    const int flat = blockIdx.x + 32 * (blockIdx.y + 8 * blockIdx.z);
    const int lg   = (flat & 7) * 128 + (flat >> 3);
    const int tile = lg & 31;
    const int h    = (lg >> 5) & 7;
    const int b    = lg >> 8;

    const int i0 = tile * 64;
    const int j0 = i0 - 128;
    const int tid = threadIdx.x;
    const int w   = tid >> 6;
    const int l   = tid & 63;
    const int lr  = l & 15;
    const int lhi = l >> 4;
    const float scale = 0.0220970869120796f;

    const size_t hbase = ((size_t)b * K_) * 512 + (size_t)h * 64;
    const unsigned short* kh = kb + hbase;
    const unsigned short* vh = vb + hbase;
    const unsigned short* qh = qb + hbase;
    unsigned short* oh = ob + hbase;

    #pragma unroll
    for (int it = 0; it < 6; ++it) {
        const int cg  = it * 4 + w;
        const int cid = cg * 64 + l;
        const int r = cid >> 3, c = cid & 7;
        const int cs = c ^ (r & 7);
        int j = j0 + r; if (j < 0) j = 0;
        gload_lds16(kh + (size_t)j * 512 + cs * 8, &Ksh[cg * 64 * 8]);
    }
    #pragma unroll
    for (int it = 0; it < 6; ++it) {
        const int cg  = it * 4 + w;
        const int cid = cg * 64 + l;
        const int blk = cid / 384;
        const int rem = cid - blk * 384;
        const int prow = rem >> 1, hf = rem & 1;
        const int a = prow >> 2, bb = prow & 3;
        const int k = (a < 24) ? (8 * a + bb) : (8 * (a - 24) + 4 + bb);
        int j = j0 + k; if (j < 0) j = 0;
        gload_lds16(vh + (size_t)j * 512 + blk * 16 + hf * 8, &Vsh[cg * 64 * 8]);
    }

    bf16x8 qa[2];
    {
        const unsigned short* qrow = qh + (size_t)(i0 + 16 * w + lr) * 512;
        qa[0] = *(const bf16x8*)(qrow + lhi * 8);
        qa[1] = *(const bf16x8*)(qrow + 32 + lhi * 8);
    }
    __syncthreads();

    const int jcbase = w & ~1;
    f32x4 sacc[10];
    #pragma unroll
    for (int jc = 0; jc < 10; ++jc) sacc[jc] = (f32x4){0.f, 0.f, 0.f, 0.f};

    __builtin_amdgcn_s_setprio(1);
    #pragma unroll
    for (int kk = 0; kk < 2; ++kk) {
        const int ch = (kk * 4 + lhi) ^ (lr & 7);
        #pragma unroll
        for (int jc = 0; jc < 10; ++jc) {
            const int row = (jcbase + jc) * 16 + lr;
            bf16x8 kf = *(const bf16x8*)&Ksh[row * 64 + ch * 8];
            sacc[jc] = __builtin_amdgcn_mfma_f32_16x16x32_bf16(
                qa[kk], kf, sacc[jc], 0, 0, 0);
        }
    }
    __builtin_amdgcn_s_setprio(0);

    unsigned short* myP = &Psh[w * 3200];
    const int lo0 = 128 - i0;
    float lsum[4] = {0.f, 0.f, 0.f, 0.f};
    #pragma unroll
    for (int jc = 0; jc < 10; ++jc) {
        const int jcol = (jcbase + jc) * 16 + lr;
        #pragma unroll
        for (int rr = 0; rr < 4; ++rr) {
            const int iloc = 16 * w + 4 * lhi + rr;
            const bool ok = (jcol >= iloc) && (jcol <= iloc + ATTN_) && (jcol >= lo0);
            const float p = ok ? __expf(fminf(sacc[jc][rr] * scale, 80.f)) : 0.f;
            lsum[rr] += p;
            myP[(4 * lhi + rr) * 200 + jcol] = f2bf(p);
        }
    }
    #pragma unroll
    for (int rr = 0; rr < 4; ++rr) {
        float s = lsum[rr];
        s += __shfl_xor(s, 1, 16);
        s += __shfl_xor(s, 2, 16);
        s += __shfl_xor(s, 4, 16);
        s += __shfl_xor(s, 8, 16);
        lsum[rr] = s;
    }

    const int kcbase = w >> 1;
    f32x4 oacc[4];
    #pragma unroll
    for (int fn = 0; fn < 4; ++fn) oacc[fn] = (f32x4){0.f, 0.f, 0.f, 0.f};
    const unsigned vbase = lds_addr(&Vsh[0]) + (unsigned)(l * 8);

    for (int kc5 = 0; kc5 < 5; ++kc5) {
        const int kc = kcbase + kc5;
        bf16x8 pa = *(const bf16x8*)&myP[lr * 200 + kc * 32 + lhi * 8];
        u32x2 vlo[4], vhi[4];
        #pragma unroll
        for (int fn = 0; fn < 4; ++fn) {
            const unsigned addr = vbase + (unsigned)((fn * 3072 + kc * 256) * 2);
            asm volatile("ds_read_b64_tr_b16 %0, %1" : "=v"(vlo[fn]) : "v"(addr));
            asm volatile("ds_read_b64_tr_b16 %0, %1 offset:3072"
                         : "=v"(vhi[fn]) : "v"(addr));
        }
        asm volatile("s_waitcnt lgkmcnt(0)" ::: "memory");
        __builtin_amdgcn_sched_barrier(0);
        __builtin_amdgcn_s_setprio(1);
        #pragma unroll
        for (int fn = 0; fn < 4; ++fn) {
            union { u32x2 h[2]; bf16x8 v; } u;
            u.h[0] = vlo[fn]; u.h[1] = vhi[fn];
            oacc[fn] = __builtin_amdgcn_mfma_f32_16x16x32_bf16(
                pa, u.v, oacc[fn], 0, 0, 0);
        }
        __builtin_amdgcn_s_setprio(0);
    }

    float inv[4];
    #pragma unroll
    for (int rr = 0; rr < 4; ++rr) inv[rr] = 1.f / lsum[rr];
    #pragma unroll
    for (int fn = 0; fn < 4; ++fn)
        #pragma unroll
        for (int rr = 0; rr < 4; ++rr) {
            const int row = i0 + 16 * w + 4 * lhi + rr;
            oh[(size_t)row * 512 + fn * 16 + lr] = f2bf(oacc[fn][rr] * inv[rr]);
        }
}

// ---------------------------------------------------------------------------
extern "C" void kernel_launch(void* const* d_in, const int* in_sizes, int n_in,
                              void* d_out, int out_size, void* d_ws, size_t ws_size,
                              hipStream_t stream)
{
    const float* query = (const float*)d_in[0];
    const float* key   = (const float*)d_in[1];
    const float* value = (const float*)d_in[2];
    const float* W_q   = (const float*)d_in[3];
    const float* b_q   = (const float*)d_in[4];
    const float* W_k   = (const float*)d_in[5];
    const float* b_k   = (const float*)d_in[6];
    const float* W_v   = (const float*)d_in[7];
    const float* b_v   = (const float*)d_in[8];
    const float* W_o   = (const float*)d_in[9];
    const float* b_o   = (const float*)d_in[10];
    float* out = (float*)d_out;

    const size_t NX = (size_t)M_ * 512;
    const size_t NW = 512 * 512;
    unsigned short* wqb = (unsigned short*)d_ws;
    unsigned short* wkb = wqb + NW;
    unsigned short* wvb = wkb + NW;
    unsigned short* wob = wvb + NW;
    unsigned short* qp  = wob + NW;
    unsigned short* kp  = qp + NX;
    unsigned short* vp  = kp + NX;
    unsigned short* ap  = vp + NX;

    const int NW8 = (int)(NW / 8);

    CvtA a;
    a.c[0] = { W_q, wqb, NW8 };
    a.c[1] = { W_k, wkb, NW8 };
    a.c[2] = { W_v, wvb, NW8 };
    a.c[3] = { W_o, wob, NW8 };
    cvt_multi<<<dim3(32, 4), 256, 0, stream>>>(a);

    QkvArgs qa;
    qa.A[0] = query; qa.A[1] = key; qa.A[2] = value;
    qa.Wt[0] = wqb;  qa.Wt[1] = wkb; qa.Wt[2] = wvb;
    qa.bias[0] = b_q; qa.bias[1] = b_k; qa.bias[2] = b_v;
    qa.C[0] = qp; qa.C[1] = kp; qa.C[2] = vp;
    gemm_qkv<<<dim3(256, 3), 512, 0, stream>>>(qa);

    attn_mfma<<<dim3(32, 8, 4), 256, 0, stream>>>(qp, kp, vp, ap);

    gemm_bf16k<false><<<256, 512, 0, stream>>>(ap, wob, b_o, out);
}